// Round 1
// baseline (257.173 us; speedup 1.0000x reference)
//
#include <hip/hip_runtime.h>

#define BB 16
#define TT 256
#define NN 2048
#define TC 32            // t-chunk per block
#define WSBASE 16        // scalar slots before per-point arrays

// ws float layout:
//  [0] recon numerator   [1] temporal numerator   [2] num_vel
//  [3] identity sum      [4] num_visible
//  [WSBASE + k*NN + n], k=0..12 : cnt, sp0..2, qp0..2, sg0..2, qg0..2

__device__ __forceinline__ float waveReduceSum(float v) {
#pragma unroll
  for (int o = 32; o > 0; o >>= 1) v += __shfl_down(v, o, 64);
  return v;
}

__global__ __launch_bounds__(256) void stats_kernel(
    const float* __restrict__ pred, const float* __restrict__ gt,
    const float* __restrict__ vis, float* __restrict__ ws) {
  const int n  = blockIdx.x * 256 + threadIdx.x;
  const int b  = blockIdx.y;
  const int t0 = blockIdx.z * TC;
  const int tstart = (t0 == 0) ? 0 : t0 - 1;  // preload prev frame at chunk boundary

  float cnt = 0.f;
  float sp0 = 0, sp1 = 0, sp2 = 0, qp0 = 0, qp1 = 0, qp2 = 0;
  float sg0 = 0, sg1 = 0, sg2 = 0, qg0 = 0, qg1 = 0, qg2 = 0;
  float recon = 0, temporal = 0, nvel = 0;
  float pm = 0, pp0 = 0, pp1 = 0, pp2 = 0, pg0 = 0, pg1 = 0, pg2 = 0;

  for (int t = tstart; t < t0 + TC; ++t) {
    size_t idx = ((size_t)(b * TT + t) * NN + n);
    float v = vis[idx];
    float m = (v > 0.5f) ? 1.f : 0.f;
    size_t i3 = idx * 3;
    float a0 = pred[i3 + 0], a1 = pred[i3 + 1], a2 = pred[i3 + 2];
    float g0 = gt[i3 + 0],  g1 = gt[i3 + 1],  g2 = gt[i3 + 2];

    if (t >= t0) {  // stats owned by this chunk (uniform branch)
      cnt += m;
      sp0 += m * a0; sp1 += m * a1; sp2 += m * a2;
      qp0 += m * a0 * a0; qp1 += m * a1 * a1; qp2 += m * a2 * a2;
      sg0 += m * g0; sg1 += m * g1; sg2 += m * g2;
      qg0 += m * g0 * g0; qg1 += m * g1 * g1; qg2 += m * g2 * g2;
      float d0 = a0 - g0, d1 = a1 - g1, d2 = a2 - g2;
      recon += m * (d0 * d0 + d1 * d1 + 2.f * d2 * d2);
    }
    if (t > tstart) {  // velocity pair (t-1, t); uniform branch
      float mv = m * pm;
      float vx = (a0 - pp0) - (g0 - pg0);
      float vy = (a1 - pp1) - (g1 - pg1);
      float vz = (a2 - pp2) - (g2 - pg2);
      temporal += mv * (vx * vx + vy * vy + vz * vz);
      nvel += mv;
    }
    pm = m; pp0 = a0; pp1 = a1; pp2 = a2; pg0 = g0; pg1 = g1; pg2 = g2;
  }

  // per-point partials (each thread owns one point within this block)
  float* pts = ws + WSBASE;
  atomicAdd(&pts[0 * NN + n], cnt);
  atomicAdd(&pts[1 * NN + n], sp0);
  atomicAdd(&pts[2 * NN + n], sp1);
  atomicAdd(&pts[3 * NN + n], sp2);
  atomicAdd(&pts[4 * NN + n], qp0);
  atomicAdd(&pts[5 * NN + n], qp1);
  atomicAdd(&pts[6 * NN + n], qp2);
  atomicAdd(&pts[7 * NN + n], sg0);
  atomicAdd(&pts[8 * NN + n], sg1);
  atomicAdd(&pts[9 * NN + n], sg2);
  atomicAdd(&pts[10 * NN + n], qg0);
  atomicAdd(&pts[11 * NN + n], qg1);
  atomicAdd(&pts[12 * NN + n], qg2);

  // global scalars: block reduce, then one atomic per scalar
  __shared__ float sred[3][4];
  float r0 = waveReduceSum(recon);
  float r1 = waveReduceSum(temporal);
  float r2 = waveReduceSum(nvel);
  int lane = threadIdx.x & 63, w = threadIdx.x >> 6;
  if (lane == 0) { sred[0][w] = r0; sred[1][w] = r1; sred[2][w] = r2; }
  __syncthreads();
  if (threadIdx.x < 3) {
    float s = sred[threadIdx.x][0] + sred[threadIdx.x][1] +
              sred[threadIdx.x][2] + sred[threadIdx.x][3];
    atomicAdd(&ws[threadIdx.x], s);
  }
}

__global__ __launch_bounds__(256) void identity_kernel(float* __restrict__ ws) {
  const int n = blockIdx.x * 256 + threadIdx.x;
  const float* pts = ws + WSBASE;
  float c   = pts[0 * NN + n];
  float sp0 = pts[1 * NN + n], sp1 = pts[2 * NN + n], sp2 = pts[3 * NN + n];
  float qp0 = pts[4 * NN + n], qp1 = pts[5 * NN + n], qp2 = pts[6 * NN + n];
  float sg0 = pts[7 * NN + n], sg1 = pts[8 * NN + n], sg2 = pts[9 * NN + n];
  float qg0 = pts[10 * NN + n], qg1 = pts[11 * NN + n], qg2 = pts[12 * NN + n];

  float inv = 1.f / fmaxf(c, 1.f);        // = 1/c for c>=1; sums are 0 when c==0
  float dv  = 1.f / fmaxf(c - 1.f, 1.f);  // unbiased divisor
  float pv0 = (qp0 - sp0 * sp0 * inv) * dv;
  float pv1 = (qp1 - sp1 * sp1 * inv) * dv;
  float pv2 = (qp2 - sp2 * sp2 * inv) * dv;
  float gv0 = (qg0 - sg0 * sg0 * inv) * dv;
  float gv1 = (qg1 - sg1 * sg1 * inv) * dv;
  float gv2 = (qg2 - sg2 * sg2 * inv) * dv;

  float num = fabsf(pv0 - gv0) + fabsf(pv1 - gv1) + fabsf(pv2 - gv2);
  float den = gv0 + gv1 + gv2 + 1e-6f;
  float contrib = (c > 1.f) ? (num / den) : 0.f;

  __shared__ float sred[2][4];
  float r0 = waveReduceSum(contrib);
  float r1 = waveReduceSum(c);
  int lane = threadIdx.x & 63, w = threadIdx.x >> 6;
  if (lane == 0) { sred[0][w] = r0; sred[1][w] = r1; }
  __syncthreads();
  if (threadIdx.x < 2) {
    float s = sred[threadIdx.x][0] + sred[threadIdx.x][1] +
              sred[threadIdx.x][2] + sred[threadIdx.x][3];
    atomicAdd(&ws[3 + threadIdx.x], s);
  }
}

__global__ void finalize_kernel(const float* __restrict__ ws, float* __restrict__ out) {
  float nv = ws[4];
  float recon = (nv > 0.f) ? ws[0] / fmaxf(nv, 1.f) : 0.f;
  float nvel = ws[2];
  float temporal = (nvel > 0.f) ? ws[1] / fmaxf(nvel, 1.f) : 0.f;
  float identity = ws[3] / (float)NN;

  float rl = recon, tl = temporal, il = identity;
  bool all_pos = (rl > 0.f) && (tl > 0.f) && (il > 0.f);
  float maxc = fmaxf(rl, fmaxf(tl, il));
  float target = maxc / 3.f;
  float thresh = 10.f * target;
  float rw = (all_pos && rl > thresh) ? 1.0f * target / fmaxf(rl, 1e-30f) : 1.0f;
  float tw = (all_pos && tl > thresh) ? 0.5f * target / fmaxf(tl, 1e-30f) : 0.5f;
  float iw = (all_pos && il > thresh) ? 0.1f * target / fmaxf(il, 1e-30f) : 0.1f;

  out[0] = rw * recon + tw * temporal + iw * identity;
  out[1] = recon;
  out[2] = temporal;
  out[3] = identity;
}

extern "C" void kernel_launch(void* const* d_in, const int* in_sizes, int n_in,
                              void* d_out, int out_size, void* d_ws, size_t ws_size,
                              hipStream_t stream) {
  const float* pred = (const float*)d_in[0];
  const float* gt   = (const float*)d_in[1];
  const float* vis  = (const float*)d_in[2];
  float* out = (float*)d_out;
  float* ws  = (float*)d_ws;

  hipMemsetAsync(d_ws, 0, (WSBASE + 13 * NN) * sizeof(float), stream);

  dim3 g1(NN / 256, BB, TT / TC);
  stats_kernel<<<g1, 256, 0, stream>>>(pred, gt, vis, ws);
  identity_kernel<<<dim3(NN / 256), 256, 0, stream>>>(ws);
  finalize_kernel<<<1, 1, 0, stream>>>(ws, out);
}

// Round 2
// 255.078 us; speedup vs baseline: 1.0082x; 1.0082x over previous
//
#include <hip/hip_runtime.h>

#define BB 16
#define TT 256
#define NN 2048
#define TC 32            // t-chunk per block
#define WSBASE 16        // scalar slots before per-point arrays

// ws float layout:
//  [0] recon numerator   [1] temporal numerator   [2] num_vel
//  [3] identity sum      [4] num_visible
//  [WSBASE + k*NN + n], k=0..12 : cnt, sp0..2, qp0..2, sg0..2, qg0..2

__device__ __forceinline__ float waveReduceSum(float v) {
#pragma unroll
  for (int o = 32; o > 0; o >>= 1) v += __shfl_down(v, o, 64);
  return v;
}

struct Frame { float v, a0, a1, a2, g0, g1, g2; };

__device__ __forceinline__ Frame loadF(const float* __restrict__ vp,
                                       const float* __restrict__ pp,
                                       const float* __restrict__ gp) {
  Frame f;
  f.v  = *vp;
  f.a0 = pp[0]; f.a1 = pp[1]; f.a2 = pp[2];
  f.g0 = gp[0]; f.g1 = gp[1]; f.g2 = gp[2];
  return f;
}

__global__ __launch_bounds__(256) void stats_kernel(
    const float* __restrict__ pred, const float* __restrict__ gt,
    const float* __restrict__ vis, float* __restrict__ ws) {
  const int n  = blockIdx.x * 256 + threadIdx.x;
  const int b  = blockIdx.y;
  const int t0 = blockIdx.z * TC;
  const int tstart = (t0 == 0) ? 0 : t0 - 1;  // boundary frame for velocity
  const int tend   = t0 + TC - 1;

  // per-thread streaming pointers, advanced one frame per step
  const float* vp = vis  + (size_t)(b * TT + tstart) * NN + n;
  const float* pp = pred + ((size_t)(b * TT + tstart) * NN + n) * 3;
  const float* gp = gt   + ((size_t)(b * TT + tstart) * NN + n) * 3;

  float cnt = 0.f;
  float sp0 = 0, sp1 = 0, sp2 = 0, qp0 = 0, qp1 = 0, qp2 = 0;
  float sg0 = 0, sg1 = 0, sg2 = 0, qg0 = 0, qg1 = 0, qg2 = 0;
  float recon = 0, temporal = 0, nvel = 0;

#define ACCUM_STATS(f, m)                                                \
  do {                                                                   \
    cnt += (m);                                                          \
    sp0 += (m) * (f).a0; sp1 += (m) * (f).a1; sp2 += (m) * (f).a2;       \
    qp0 += (m) * (f).a0 * (f).a0; qp1 += (m) * (f).a1 * (f).a1;          \
    qp2 += (m) * (f).a2 * (f).a2;                                        \
    sg0 += (m) * (f).g0; sg1 += (m) * (f).g1; sg2 += (m) * (f).g2;       \
    qg0 += (m) * (f).g0 * (f).g0; qg1 += (m) * (f).g1 * (f).g1;          \
    qg2 += (m) * (f).g2 * (f).g2;                                        \
    float d0 = (f).a0 - (f).g0, d1 = (f).a1 - (f).g1, d2 = (f).a2 - (f).g2; \
    recon += (m) * (d0 * d0 + d1 * d1 + 2.f * d2 * d2);                  \
  } while (0)

#define ACCUM_VEL(p, c, mp, mc)                                          \
  do {                                                                   \
    float mv = (mp) * (mc);                                              \
    float vx = ((c).a0 - (p).a0) - ((c).g0 - (p).g0);                    \
    float vy = ((c).a1 - (p).a1) - ((c).g1 - (p).g1);                    \
    float vz = ((c).a2 - (p).a2) - ((c).g2 - (p).g2);                    \
    temporal += mv * (vx * vx + vy * vy + vz * vz);                      \
    nvel += mv;                                                          \
  } while (0)

  // software pipeline: prev / cur in regs, next frame's load always in flight
  Frame prev = loadF(vp, pp, gp); vp += NN; pp += 3 * NN; gp += 3 * NN;
  Frame cur  = loadF(vp, pp, gp); vp += NN; pp += 3 * NN; gp += 3 * NN;
  float mprev = (prev.v > 0.5f) ? 1.f : 0.f;

  if (t0 == 0) ACCUM_STATS(prev, mprev);  // frame 0 stats owned by first chunk

  // every loop frame t in [tstart+1, tend] gets stats + velocity (branch-free)
#pragma unroll 4
  for (int t = tstart + 1; t < tend; ++t) {
    Frame nx = loadF(vp, pp, gp);  // prefetch t+1, in flight during compute
    vp += NN; pp += 3 * NN; gp += 3 * NN;
    float mc = (cur.v > 0.5f) ? 1.f : 0.f;
    ACCUM_STATS(cur, mc);
    ACCUM_VEL(prev, cur, mprev, mc);
    prev = cur; mprev = mc; cur = nx;
  }
  {  // tail frame tend (no prefetch)
    float mc = (cur.v > 0.5f) ? 1.f : 0.f;
    ACCUM_STATS(cur, mc);
    ACCUM_VEL(prev, cur, mprev, mc);
  }

  // per-point partials (each thread owns one point within this block)
  float* pts = ws + WSBASE;
  atomicAdd(&pts[0 * NN + n], cnt);
  atomicAdd(&pts[1 * NN + n], sp0);
  atomicAdd(&pts[2 * NN + n], sp1);
  atomicAdd(&pts[3 * NN + n], sp2);
  atomicAdd(&pts[4 * NN + n], qp0);
  atomicAdd(&pts[5 * NN + n], qp1);
  atomicAdd(&pts[6 * NN + n], qp2);
  atomicAdd(&pts[7 * NN + n], sg0);
  atomicAdd(&pts[8 * NN + n], sg1);
  atomicAdd(&pts[9 * NN + n], sg2);
  atomicAdd(&pts[10 * NN + n], qg0);
  atomicAdd(&pts[11 * NN + n], qg1);
  atomicAdd(&pts[12 * NN + n], qg2);

  // global scalars: block reduce, then one atomic per scalar
  __shared__ float sred[3][4];
  float r0 = waveReduceSum(recon);
  float r1 = waveReduceSum(temporal);
  float r2 = waveReduceSum(nvel);
  int lane = threadIdx.x & 63, w = threadIdx.x >> 6;
  if (lane == 0) { sred[0][w] = r0; sred[1][w] = r1; sred[2][w] = r2; }
  __syncthreads();
  if (threadIdx.x < 3) {
    float s = sred[threadIdx.x][0] + sred[threadIdx.x][1] +
              sred[threadIdx.x][2] + sred[threadIdx.x][3];
    atomicAdd(&ws[threadIdx.x], s);
  }
}

__global__ __launch_bounds__(256) void identity_kernel(float* __restrict__ ws) {
  const int n = blockIdx.x * 256 + threadIdx.x;
  const float* pts = ws + WSBASE;
  float c   = pts[0 * NN + n];
  float sp0 = pts[1 * NN + n], sp1 = pts[2 * NN + n], sp2 = pts[3 * NN + n];
  float qp0 = pts[4 * NN + n], qp1 = pts[5 * NN + n], qp2 = pts[6 * NN + n];
  float sg0 = pts[7 * NN + n], sg1 = pts[8 * NN + n], sg2 = pts[9 * NN + n];
  float qg0 = pts[10 * NN + n], qg1 = pts[11 * NN + n], qg2 = pts[12 * NN + n];

  float inv = 1.f / fmaxf(c, 1.f);        // = 1/c for c>=1; sums are 0 when c==0
  float dv  = 1.f / fmaxf(c - 1.f, 1.f);  // unbiased divisor
  float pv0 = (qp0 - sp0 * sp0 * inv) * dv;
  float pv1 = (qp1 - sp1 * sp1 * inv) * dv;
  float pv2 = (qp2 - sp2 * sp2 * inv) * dv;
  float gv0 = (qg0 - sg0 * sg0 * inv) * dv;
  float gv1 = (qg1 - sg1 * sg1 * inv) * dv;
  float gv2 = (qg2 - sg2 * sg2 * inv) * dv;

  float num = fabsf(pv0 - gv0) + fabsf(pv1 - gv1) + fabsf(pv2 - gv2);
  float den = gv0 + gv1 + gv2 + 1e-6f;
  float contrib = (c > 1.f) ? (num / den) : 0.f;

  __shared__ float sred[2][4];
  float r0 = waveReduceSum(contrib);
  float r1 = waveReduceSum(c);
  int lane = threadIdx.x & 63, w = threadIdx.x >> 6;
  if (lane == 0) { sred[0][w] = r0; sred[1][w] = r1; }
  __syncthreads();
  if (threadIdx.x < 2) {
    float s = sred[threadIdx.x][0] + sred[threadIdx.x][1] +
              sred[threadIdx.x][2] + sred[threadIdx.x][3];
    atomicAdd(&ws[3 + threadIdx.x], s);
  }
}

__global__ void finalize_kernel(const float* __restrict__ ws, float* __restrict__ out) {
  float nv = ws[4];
  float recon = (nv > 0.f) ? ws[0] / fmaxf(nv, 1.f) : 0.f;
  float nvel = ws[2];
  float temporal = (nvel > 0.f) ? ws[1] / fmaxf(nvel, 1.f) : 0.f;
  float identity = ws[3] / (float)NN;

  float rl = recon, tl = temporal, il = identity;
  bool all_pos = (rl > 0.f) && (tl > 0.f) && (il > 0.f);
  float maxc = fmaxf(rl, fmaxf(tl, il));
  float target = maxc / 3.f;
  float thresh = 10.f * target;
  float rw = (all_pos && rl > thresh) ? 1.0f * target / fmaxf(rl, 1e-30f) : 1.0f;
  float tw = (all_pos && tl > thresh) ? 0.5f * target / fmaxf(tl, 1e-30f) : 0.5f;
  float iw = (all_pos && il > thresh) ? 0.1f * target / fmaxf(il, 1e-30f) : 0.1f;

  out[0] = rw * recon + tw * temporal + iw * identity;
  out[1] = recon;
  out[2] = temporal;
  out[3] = identity;
}

extern "C" void kernel_launch(void* const* d_in, const int* in_sizes, int n_in,
                              void* d_out, int out_size, void* d_ws, size_t ws_size,
                              hipStream_t stream) {
  const float* pred = (const float*)d_in[0];
  const float* gt   = (const float*)d_in[1];
  const float* vis  = (const float*)d_in[2];
  float* out = (float*)d_out;
  float* ws  = (float*)d_ws;

  hipMemsetAsync(d_ws, 0, (WSBASE + 13 * NN) * sizeof(float), stream);

  dim3 g1(NN / 256, BB, TT / TC);
  stats_kernel<<<g1, 256, 0, stream>>>(pred, gt, vis, ws);
  identity_kernel<<<dim3(NN / 256), 256, 0, stream>>>(ws);
  finalize_kernel<<<1, 1, 0, stream>>>(ws, out);
}

// Round 3
// 254.220 us; speedup vs baseline: 1.0116x; 1.0034x over previous
//
#include <hip/hip_runtime.h>

#define BB 16
#define TT 256
#define NN 2048
#define TC 16            // t-chunk per block (16 -> 2048 blocks -> 8 blocks/CU)
#define NSLICE 8         // atomic contention spread (slice = b & 7)
#define WSBASE 16        // scalar slots before per-point arrays

// ws float layout:
//  [0] recon numerator   [1] temporal numerator   [2] num_vel
//  [3] identity sum      [4] num_visible
//  [WSBASE + (s*13 + k)*NN + n], s=0..7, k=0..12 : cnt, sp0..2, qp0..2, sg0..2, qg0..2

__device__ __forceinline__ float waveReduceSum(float v) {
#pragma unroll
  for (int o = 32; o > 0; o >>= 1) v += __shfl_down(v, o, 64);
  return v;
}

__global__ __launch_bounds__(256, 8) void stats_kernel(
    const float* __restrict__ pred, const float* __restrict__ gt,
    const float* __restrict__ vis, float* __restrict__ ws) {
  const int n  = blockIdx.x * 256 + threadIdx.x;
  const int b  = blockIdx.y;
  const int t0 = blockIdx.z * TC;

  const size_t frame0 = (size_t)(b * TT + t0) * NN + n;
  const float3* __restrict__ pp = (const float3*)pred + frame0;
  const float3* __restrict__ gp = (const float3*)gt + frame0;
  const float*  __restrict__ vp = vis + frame0;

  float cnt = 0.f;
  float sp0 = 0, sp1 = 0, sp2 = 0, qp0 = 0, qp1 = 0, qp2 = 0;
  float sg0 = 0, sg1 = 0, sg2 = 0, qg0 = 0, qg1 = 0, qg2 = 0;
  float recon = 0, temporal = 0, nvel = 0;

  // boundary frame t0-1 (velocity only). For t0==0 load frame 0 with mask 0.
  float3 ppv, pgv;
  float mprev;
  {
    const long off = (t0 == 0) ? 0 : -(long)NN;
    ppv = pp[off];
    pgv = gp[off];
    float v = vp[off];
    mprev = (t0 != 0 && v > 0.5f) ? 1.f : 0.f;
  }

#pragma unroll
  for (int i = 0; i < TC; ++i) {
    float3 a = pp[(size_t)i * NN];
    float3 g = gp[(size_t)i * NN];
    float v = vp[(size_t)i * NN];
    float m = (v > 0.5f) ? 1.f : 0.f;

    // stats (owned by this chunk)
    cnt += m;
    sp0 += m * a.x; sp1 += m * a.y; sp2 += m * a.z;
    qp0 += m * a.x * a.x; qp1 += m * a.y * a.y; qp2 += m * a.z * a.z;
    sg0 += m * g.x; sg1 += m * g.y; sg2 += m * g.z;
    qg0 += m * g.x * g.x; qg1 += m * g.y * g.y; qg2 += m * g.z * g.z;
    float d0 = a.x - g.x, d1 = a.y - g.y, d2 = a.z - g.z;
    recon += m * (d0 * d0 + d1 * d1 + 2.f * d2 * d2);

    // velocity pair (t-1, t)
    float mv = m * mprev;
    float vx = (a.x - ppv.x) - (g.x - pgv.x);
    float vy = (a.y - ppv.y) - (g.y - pgv.y);
    float vz = (a.z - ppv.z) - (g.z - pgv.z);
    temporal += mv * (vx * vx + vy * vy + vz * vz);
    nvel += mv;

    ppv = a; pgv = g; mprev = m;
  }

  // per-point partials, spread over NSLICE slices to cut same-address contention
  float* pts = ws + WSBASE + (size_t)(b & (NSLICE - 1)) * 13 * NN;
  atomicAdd(&pts[0 * NN + n], cnt);
  atomicAdd(&pts[1 * NN + n], sp0);
  atomicAdd(&pts[2 * NN + n], sp1);
  atomicAdd(&pts[3 * NN + n], sp2);
  atomicAdd(&pts[4 * NN + n], qp0);
  atomicAdd(&pts[5 * NN + n], qp1);
  atomicAdd(&pts[6 * NN + n], qp2);
  atomicAdd(&pts[7 * NN + n], sg0);
  atomicAdd(&pts[8 * NN + n], sg1);
  atomicAdd(&pts[9 * NN + n], sg2);
  atomicAdd(&pts[10 * NN + n], qg0);
  atomicAdd(&pts[11 * NN + n], qg1);
  atomicAdd(&pts[12 * NN + n], qg2);

  // global scalars: block reduce, then one atomic per scalar
  __shared__ float sred[3][4];
  float r0 = waveReduceSum(recon);
  float r1 = waveReduceSum(temporal);
  float r2 = waveReduceSum(nvel);
  int lane = threadIdx.x & 63, w = threadIdx.x >> 6;
  if (lane == 0) { sred[0][w] = r0; sred[1][w] = r1; sred[2][w] = r2; }
  __syncthreads();
  if (threadIdx.x < 3) {
    float s = sred[threadIdx.x][0] + sred[threadIdx.x][1] +
              sred[threadIdx.x][2] + sred[threadIdx.x][3];
    atomicAdd(&ws[threadIdx.x], s);
  }
}

__global__ __launch_bounds__(256) void identity_kernel(float* __restrict__ ws) {
  const int n = blockIdx.x * 256 + threadIdx.x;
  const float* base = ws + WSBASE;
  float st[13];
#pragma unroll
  for (int k = 0; k < 13; ++k) st[k] = 0.f;
#pragma unroll
  for (int s = 0; s < NSLICE; ++s) {
    const float* pts = base + (size_t)s * 13 * NN;
#pragma unroll
    for (int k = 0; k < 13; ++k) st[k] += pts[k * NN + n];
  }
  float c = st[0];
  float sp0 = st[1], sp1 = st[2], sp2 = st[3];
  float qp0 = st[4], qp1 = st[5], qp2 = st[6];
  float sg0 = st[7], sg1 = st[8], sg2 = st[9];
  float qg0 = st[10], qg1 = st[11], qg2 = st[12];

  float inv = 1.f / fmaxf(c, 1.f);        // = 1/c for c>=1; sums are 0 when c==0
  float dv  = 1.f / fmaxf(c - 1.f, 1.f);  // unbiased divisor
  float pv0 = (qp0 - sp0 * sp0 * inv) * dv;
  float pv1 = (qp1 - sp1 * sp1 * inv) * dv;
  float pv2 = (qp2 - sp2 * sp2 * inv) * dv;
  float gv0 = (qg0 - sg0 * sg0 * inv) * dv;
  float gv1 = (qg1 - sg1 * sg1 * inv) * dv;
  float gv2 = (qg2 - sg2 * sg2 * inv) * dv;

  float num = fabsf(pv0 - gv0) + fabsf(pv1 - gv1) + fabsf(pv2 - gv2);
  float den = gv0 + gv1 + gv2 + 1e-6f;
  float contrib = (c > 1.f) ? (num / den) : 0.f;

  __shared__ float sred[2][4];
  float r0 = waveReduceSum(contrib);
  float r1 = waveReduceSum(c);
  int lane = threadIdx.x & 63, w = threadIdx.x >> 6;
  if (lane == 0) { sred[0][w] = r0; sred[1][w] = r1; }
  __syncthreads();
  if (threadIdx.x < 2) {
    float s = sred[threadIdx.x][0] + sred[threadIdx.x][1] +
              sred[threadIdx.x][2] + sred[threadIdx.x][3];
    atomicAdd(&ws[3 + threadIdx.x], s);
  }
}

__global__ void finalize_kernel(const float* __restrict__ ws, float* __restrict__ out) {
  float nv = ws[4];
  float recon = (nv > 0.f) ? ws[0] / fmaxf(nv, 1.f) : 0.f;
  float nvel = ws[2];
  float temporal = (nvel > 0.f) ? ws[1] / fmaxf(nvel, 1.f) : 0.f;
  float identity = ws[3] / (float)NN;

  float rl = recon, tl = temporal, il = identity;
  bool all_pos = (rl > 0.f) && (tl > 0.f) && (il > 0.f);
  float maxc = fmaxf(rl, fmaxf(tl, il));
  float target = maxc / 3.f;
  float thresh = 10.f * target;
  float rw = (all_pos && rl > thresh) ? 1.0f * target / fmaxf(rl, 1e-30f) : 1.0f;
  float tw = (all_pos && tl > thresh) ? 0.5f * target / fmaxf(tl, 1e-30f) : 0.5f;
  float iw = (all_pos && il > thresh) ? 0.1f * target / fmaxf(il, 1e-30f) : 0.1f;

  out[0] = rw * recon + tw * temporal + iw * identity;
  out[1] = recon;
  out[2] = temporal;
  out[3] = identity;
}

extern "C" void kernel_launch(void* const* d_in, const int* in_sizes, int n_in,
                              void* d_out, int out_size, void* d_ws, size_t ws_size,
                              hipStream_t stream) {
  const float* pred = (const float*)d_in[0];
  const float* gt   = (const float*)d_in[1];
  const float* vis  = (const float*)d_in[2];
  float* out = (float*)d_out;
  float* ws  = (float*)d_ws;

  hipMemsetAsync(d_ws, 0, (WSBASE + (size_t)NSLICE * 13 * NN) * sizeof(float), stream);

  dim3 g1(NN / 256, BB, TT / TC);
  stats_kernel<<<g1, 256, 0, stream>>>(pred, gt, vis, ws);
  identity_kernel<<<dim3(NN / 256), 256, 0, stream>>>(ws);
  finalize_kernel<<<1, 1, 0, stream>>>(ws, out);
}